// Round 21
// baseline (187.423 us; speedup 1.0000x reference)
//
#include <hip/hip_runtime.h>

#define H 1024
#define W 1024
#define TY 8
#define NT 64               /* one wave per block */
#define RS 10               /* ring slots (distance 9 + 1) */
#define NG 66               /* uint4 groups/slot: 1 halo + 64 own + 1 halo */
#define NBK 64              /* reduction buckets */

__global__ void ncc_zero(double* acc) {
    if (threadIdx.x < NBK) acc[threadIdx.x] = 0.0;
}

__global__ void ncc_finalize(const double* __restrict__ acc, float* __restrict__ out) {
    double s = 0.0;
    #pragma unroll
    for (int i = 0; i < NBK; ++i) s += acc[i];
    out[0] = 1.0f - (float)(s * (1.0 / 8388608.0));
}

__device__ __forceinline__ unsigned pk2(float lo, float hi) {
    unsigned r;
    asm("v_cvt_pk_bf16_f32 %0, %1, %2" : "=v"(r) : "v"(lo), "v"(hi));
    return r;
}
__device__ __forceinline__ float ulo(unsigned u) { return __uint_as_float(u << 16); }
__device__ __forceinline__ float uhi(unsigned u) { return __uint_as_float(u & 0xffff0000u); }

__global__ __launch_bounds__(NT) void ncc_main(
    const float* __restrict__ Jg,  // y_pred
    const float* __restrict__ Ig,  // y_true
    double* __restrict__ acc)
{
    __shared__ uint4 ring[RS][NG];   // bf16 rows {i01,i23,j01,j23}/group: 10.56 KB

    const int n     = blockIdx.x;
    const int b     = n & 7;         // image (== XCD round-robin)
    const int rest  = n >> 3;
    const int panel = rest & 3;
    const int strip = rest >> 2;
    const int y0    = strip * TY;
    const int lane  = threadIdx.x;
    const int wb    = panel << 8;
    const int x0    = wb + (lane << 2);

    const float* __restrict__ Ib = Ig + (size_t)b * (H * W);
    const float* __restrict__ Jb = Jg + (size_t)b * (H * W);

    // edge lanes own the halo: lane 0 -> left group 0 (cols wb-4..wb-1),
    // lane 63 -> right group 65 (cols wb+256..wb+259)
    const bool  eL  = (lane == 0);
    const bool  eR  = (lane == NT - 1);
    const bool  isE = eL || eR;
    const int   hx  = eL ? (wb - 4) : (wb + 256);
    const float mhx = (isE && (unsigned)hx <= (unsigned)(W - 4)) ? 1.0f : 0.0f;
    const int   hxc = min(max(hx, 0), W - 4);
    const int   hg  = eL ? 0 : (NG - 1);

    // own vertical sums (4 cols) + edge-lane halo vertical sums (4 halo cols)
    float sI[4]={0,0,0,0}, sJ[4]={0,0,0,0}, sII[4]={0,0,0,0}, sJJ[4]={0,0,0,0}, sIJ[4]={0,0,0,0};
    float4 hE0={0,0,0,0}, hE1={0,0,0,0}, hE2={0,0,0,0}, hE3={0,0,0,0}, hE4={0,0,0,0};

    float accv = 0.0f;
    const float inv = 1.0f / 81.0f;

    float4 Pi, Pj, Phi = {0,0,0,0}, Phj = {0,0,0,0};
    float  Pm;

#define FLOAD(yy) do {                                                              \
        const int r_ = (yy);                                                        \
        Pm = ((unsigned)r_ < (unsigned)H) ? 1.0f : 0.0f;                            \
        const int rc_ = min(max(r_, 0), H - 1);                                     \
        Pi = *(const float4*)(Ib + (size_t)rc_ * W + x0);                           \
        Pj = *(const float4*)(Jb + (size_t)rc_ * W + x0);                           \
        if (isE) {                                                                  \
            Phi = *(const float4*)(Ib + (size_t)rc_ * W + hxc);                     \
            Phj = *(const float4*)(Jb + (size_t)rc_ * W + hxc);                     \
        }                                                                           \
    } while (0)

// pack P-regs -> ring slot; leaves pkv (own) and hkv (edge halo) for the folds
#define PACKW(sl) do {                                                              \
        pkv.x = pk2(Pi.x * Pm, Pi.y * Pm);                                          \
        pkv.y = pk2(Pi.z * Pm, Pi.w * Pm);                                          \
        pkv.z = pk2(Pj.x * Pm, Pj.y * Pm);                                          \
        pkv.w = pk2(Pj.z * Pm, Pj.w * Pm);                                          \
        ring[sl][lane + 1] = pkv;                                                   \
        if (isE) {                                                                  \
            const float mm_ = Pm * mhx;                                             \
            hkv.x = pk2(Phi.x * mm_, Phi.y * mm_);                                  \
            hkv.y = pk2(Phi.z * mm_, Phi.w * mm_);                                  \
            hkv.z = pk2(Phj.x * mm_, Phj.y * mm_);                                  \
            hkv.w = pk2(Phj.z * mm_, Phj.w * mm_);                                  \
            ring[sl][hg] = hkv;                                                     \
        }                                                                           \
    } while (0)

#define FOLDOWN(G, SG) do {                                                         \
        const float i0=ulo(G.x), i1=uhi(G.x), i2=ulo(G.y), i3=uhi(G.y);             \
        const float j0=ulo(G.z), j1=uhi(G.z), j2=ulo(G.w), j3=uhi(G.w);             \
        sI[0]+=SG*i0; sI[1]+=SG*i1; sI[2]+=SG*i2; sI[3]+=SG*i3;                     \
        sJ[0]+=SG*j0; sJ[1]+=SG*j1; sJ[2]+=SG*j2; sJ[3]+=SG*j3;                     \
        sII[0]+=SG*i0*i0; sII[1]+=SG*i1*i1; sII[2]+=SG*i2*i2; sII[3]+=SG*i3*i3;     \
        sJJ[0]+=SG*j0*j0; sJJ[1]+=SG*j1*j1; sJJ[2]+=SG*j2*j2; sJJ[3]+=SG*j3*j3;     \
        sIJ[0]+=SG*i0*j0; sIJ[1]+=SG*i1*j1; sIJ[2]+=SG*i2*j2; sIJ[3]+=SG*i3*j3;     \
    } while (0)

// edge lanes: fold packed halo group into halo vertical sums
#define FOLDEDGE(G, SG) do {                                                        \
        const float i0=ulo(G.x), i1=uhi(G.x), i2=ulo(G.y), i3=uhi(G.y);             \
        const float j0=ulo(G.z), j1=uhi(G.z), j2=ulo(G.w), j3=uhi(G.w);             \
        hE0.x+=SG*i0; hE0.y+=SG*i1; hE0.z+=SG*i2; hE0.w+=SG*i3;                     \
        hE1.x+=SG*j0; hE1.y+=SG*j1; hE1.z+=SG*j2; hE1.w+=SG*j3;                     \
        hE2.x+=SG*i0*i0; hE2.y+=SG*i1*i1; hE2.z+=SG*i2*i2; hE2.w+=SG*i3*i3;         \
        hE3.x+=SG*j0*j0; hE3.y+=SG*j1*j1; hE3.z+=SG*j2*j2; hE3.w+=SG*j3*j3;         \
        hE4.x+=SG*i0*j0; hE4.y+=SG*i1*j1; hE4.z+=SG*i2*j2; hE4.w+=SG*i3*j3;         \
    } while (0)

// neighbor exchange: a = left lane's S-group (cols x-4..x-1), c = right lane's
#define SHFLX(S, A, C, HE) do {                                                     \
        A.x = __shfl_up(S[0], 1);  A.y = __shfl_up(S[1], 1);                        \
        A.z = __shfl_up(S[2], 1);  A.w = __shfl_up(S[3], 1);                        \
        C.x = __shfl_down(S[0], 1); C.y = __shfl_down(S[1], 1);                     \
        C.z = __shfl_down(S[2], 1); C.w = __shfl_down(S[3], 1);                     \
        A = eL ? HE : A;                                                            \
        C = eR ? HE : C;                                                            \
    } while (0)

#define HTAP(a, cg, T, o) do {                                                      \
        float s_ = a.x + a.y + a.z + a.w + cg.x + T;                                \
        o[0] = s_; s_ += cg.y - a.x;                                                \
        o[1] = s_; s_ += cg.z - a.y;                                                \
        o[2] = s_; s_ += cg.w - a.z;                                                \
        o[3] = s_;                                                                  \
    } while (0)

    // ---- init: rows y0-4 .. y0+4 -> ring slots 0..8, folded (+) ----
    FLOAD(y0 - 4);
    #pragma unroll 1
    for (int r = 0; r < 9; ++r) {
        uint4 pkv, hkv = make_uint4(0, 0, 0, 0);
        PACKW(r);
        FLOAD(y0 - 3 + r);             // r==8 loads y0+5: first enter row
        FOLDOWN(pkv, 1.0f);
        if (isE) FOLDEDGE(hkv, 1.0f);
    }
    asm volatile("" ::: "memory");

    // ---- main: TY rows, one per iteration ----
    int ls = 0, es = 9;
    #pragma unroll 1
    for (int k = 0; k < TY; ++k) {
        // 1) neighbor exchange of window(y0+k) vertical sums (register shuffles)
        float4 A0, A1, A2, A3, A4, C0, C1, C2, C3, C4;
        SHFLX(sI,  A0, C0, hE0);
        SHFLX(sJ,  A1, C1, hE1);
        SHFLX(sII, A2, C2, hE2);
        SHFLX(sJJ, A3, C3, hE3);
        SHFLX(sIJ, A4, C4, hE4);

        // 2) totals of window(y0+k)
        const float T0 = sI[0]  + sI[1]  + sI[2]  + sI[3];
        const float T1 = sJ[0]  + sJ[1]  + sJ[2]  + sJ[3];
        const float T2 = sII[0] + sII[1] + sII[2] + sII[3];
        const float T3 = sJJ[0] + sJJ[1] + sJJ[2] + sJJ[3];
        const float T4 = sIJ[0] + sIJ[1] + sIJ[2] + sIJ[3];

        // 3) enter row -> ring; issue leave reads (covers shuffle latency)
        uint4 pkv, hkv = make_uint4(0, 0, 0, 0);
        PACKW(es);
        uint4 lv = ring[ls][lane + 1];
        uint4 lh = make_uint4(0, 0, 0, 0);
        if (isE) lh = ring[ls][hg];

        // 4) prefetch next enter row (global, read-once)
        FLOAD(y0 + 6 + k);

        // 5) horizontal 9-taps + cc for row y0+k
        float h0[4], h1[4], h2[4], h3[4], h4[4];
        HTAP(A0, C0, T0, h0); HTAP(A1, C1, T1, h1); HTAP(A2, C2, T2, h2);
        HTAP(A3, C3, T3, h3); HTAP(A4, C4, T4, h4);
        #pragma unroll
        for (int c = 0; c < 4; ++c) {
            const float uI    = h0[c] * inv;
            const float uJ    = h1[c] * inv;
            const float cross = h4[c] * inv - uI * uJ;
            const float Iv    = h2[c] * inv - uI * uI;
            const float Jv    = h3[c] * inv - uJ * uJ;
            accv += cross * rsqrtf(fmaxf(Iv * Jv, 1e-7f));
        }

        // 6) slide: enter(+) / leave(-) — bit-identical packed values cancel exactly
        FOLDOWN(pkv, 1.0f);
        FOLDOWN(lv, -1.0f);
        if (isE) { FOLDEDGE(hkv, 1.0f); FOLDEDGE(lh, -1.0f); }

        ls = (ls == RS - 1) ? 0 : ls + 1;
        es = (es == RS - 1) ? 0 : es + 1;
    }

#undef HTAP
#undef SHFLX
#undef FOLDEDGE
#undef FOLDOWN
#undef PACKW
#undef FLOAD

    // wave reduce -> bucketed atomics
    #pragma unroll
    for (int off = 32; off > 0; off >>= 1)
        accv += __shfl_down(accv, off);
    if (lane == 0)
        atomicAdd(&acc[n & (NBK - 1)], (double)accv);
}

extern "C" void kernel_launch(void* const* d_in, const int* in_sizes, int n_in,
                              void* d_out, int out_size, void* d_ws, size_t ws_size,
                              hipStream_t stream) {
    const float* y_pred = (const float*)d_in[0];  // Ji
    const float* y_true = (const float*)d_in[1];  // Ii
    float* out = (float*)d_out;
    double* accp = (double*)d_ws;

    ncc_zero<<<dim3(1), dim3(NBK), 0, stream>>>(accp);
    // 8 img x 4 panels x 128 strips = 4096 one-wave blocks; LDS 10.56 KB ->
    // ~15 resident blocks/CU; halo via register shuffles (no vs publish/read)
    ncc_main<<<dim3(8 * 4 * (H / TY)), dim3(NT), 0, stream>>>(y_pred, y_true, accp);
    ncc_finalize<<<dim3(1), dim3(1), 0, stream>>>(accp, out);
}

// Round 22
// 47.071 us; speedup vs baseline: 3.9817x; 3.9817x over previous
//
#include <hip/hip_runtime.h>

#define H 1024
#define W 1024
#define TY 8
#define NT 64               /* one wave per block */
#define RS 9                /* ring slots: distance-9, read-before-write same slot */
#define NG 66               /* uint4 groups/slot: 1 halo + 64 own + 1 halo */
#define LW 264              /* vs cols: 4 pad + 256 + 4 pad (bf16) */
#define NBK 64              /* reduction buckets */

__global__ void ncc_zero(double* acc) {
    if (threadIdx.x < NBK) acc[threadIdx.x] = 0.0;
}

__global__ void ncc_finalize(const double* __restrict__ acc, float* __restrict__ out) {
    double s = 0.0;
    #pragma unroll
    for (int i = 0; i < NBK; ++i) s += acc[i];
    out[0] = 1.0f - (float)(s * (1.0 / 8388608.0));
}

__device__ __forceinline__ unsigned pk2(float lo, float hi) {
    unsigned r;
    asm("v_cvt_pk_bf16_f32 %0, %1, %2" : "=v"(r) : "v"(lo), "v"(hi));
    return r;
}
__device__ __forceinline__ float ulo(unsigned u) { return __uint_as_float(u << 16); }
__device__ __forceinline__ float uhi(unsigned u) { return __uint_as_float(u & 0xffff0000u); }

__global__ __launch_bounds__(NT) void ncc_main(
    const float* __restrict__ Jg,  // y_pred
    const float* __restrict__ Ig,  // y_true
    double* __restrict__ acc)
{
    __shared__ uint4 ring[RS][NG];           // bf16 rows {i01,i23,j01,j23}: 9.28 KB
    __shared__ unsigned short vs[5][LW];     // bf16 vertical sums: 2.58 KB

    const int n     = blockIdx.x;
    const int b     = n & 7;                 // image (== XCD round-robin)
    const int rest  = n >> 3;
    const int panel = rest & 3;
    const int strip = rest >> 2;
    const int y0    = strip * TY;
    const int lane  = threadIdx.x;
    const int wb    = panel << 8;
    const int x0    = wb + (lane << 2);
    const int xw    = lane << 2;             // vs read base; own at xw+4

    const float* __restrict__ Ib = Ig + (size_t)b * (H * W);
    const float* __restrict__ Jb = Jg + (size_t)b * (H * W);

    // ring halo writers: lane 0 -> group 0 (cols wb-4..wb-1), lane 1 -> group 65
    const bool  hw  = (lane < 2);
    const int   hx  = (lane == 0) ? (wb - 4) : (wb + 256);
    const float mhx = (hw && (unsigned)hx <= (unsigned)(W - 4)) ? 1.0f : 0.0f;
    const int   hxc = min(max(hx, 0), W - 4);
    const int   hgw = (lane == 0) ? 0 : (NG - 1);

    // halo-sum owners: lanes 0..7, one col each (0-3 left, 4-7 right)
    const bool  isH   = (lane < 8);
    const int   hg8   = (lane < 4) ? 0 : (NG - 1);
    const int   hidx  = lane & 3;
    const int   hslot = (lane < 4) ? lane : (256 + lane);   // vs pad cols 0-3/260-263

    float sI[4]={0,0,0,0}, sJ[4]={0,0,0,0}, sII[4]={0,0,0,0}, sJJ[4]={0,0,0,0}, sIJ[4]={0,0,0,0};
    float hs0=0, hs1=0, hs2=0, hs3=0, hs4=0;
    float accv = 0.0f;
    const float inv = 1.0f / 81.0f;

    float4 Pi, Pj, Phi = {0,0,0,0}, Phj = {0,0,0,0};
    float  Pm;

#define FLOAD(yy) do {                                                              \
        const int r_ = (yy);                                                        \
        Pm = ((unsigned)r_ < (unsigned)H) ? 1.0f : 0.0f;                            \
        const int rc_ = min(max(r_, 0), H - 1);                                     \
        Pi = *(const float4*)(Ib + (size_t)rc_ * W + x0);                           \
        Pj = *(const float4*)(Jb + (size_t)rc_ * W + x0);                           \
        if (hw) {                                                                   \
            Phi = *(const float4*)(Ib + (size_t)rc_ * W + hxc);                     \
            Phj = *(const float4*)(Jb + (size_t)rc_ * W + hxc);                     \
        }                                                                           \
    } while (0)

#define PACKW(sl) do {                                                              \
        pkv.x = pk2(Pi.x * Pm, Pi.y * Pm);                                          \
        pkv.y = pk2(Pi.z * Pm, Pi.w * Pm);                                          \
        pkv.z = pk2(Pj.x * Pm, Pj.y * Pm);                                          \
        pkv.w = pk2(Pj.z * Pm, Pj.w * Pm);                                          \
        ring[sl][lane + 1] = pkv;                                                   \
        if (hw) {                                                                   \
            const float mm_ = Pm * mhx;                                             \
            uint4 h_;                                                               \
            h_.x = pk2(Phi.x * mm_, Phi.y * mm_);                                   \
            h_.y = pk2(Phi.z * mm_, Phi.w * mm_);                                   \
            h_.z = pk2(Phj.x * mm_, Phj.y * mm_);                                   \
            h_.w = pk2(Phj.z * mm_, Phj.w * mm_);                                   \
            ring[sl][hgw] = h_;                                                     \
        }                                                                           \
    } while (0)

#define FOLDOWN(G, SG) do {                                                         \
        const float i0=ulo(G.x), i1=uhi(G.x), i2=ulo(G.y), i3=uhi(G.y);             \
        const float j0=ulo(G.z), j1=uhi(G.z), j2=ulo(G.w), j3=uhi(G.w);             \
        sI[0]+=SG*i0; sI[1]+=SG*i1; sI[2]+=SG*i2; sI[3]+=SG*i3;                     \
        sJ[0]+=SG*j0; sJ[1]+=SG*j1; sJ[2]+=SG*j2; sJ[3]+=SG*j3;                     \
        sII[0]+=SG*i0*i0; sII[1]+=SG*i1*i1; sII[2]+=SG*i2*i2; sII[3]+=SG*i3*i3;     \
        sJJ[0]+=SG*j0*j0; sJJ[1]+=SG*j1*j1; sJJ[2]+=SG*j2*j2; sJJ[3]+=SG*j3*j3;     \
        sIJ[0]+=SG*i0*j0; sIJ[1]+=SG*i1*j1; sIJ[2]+=SG*i2*j2; sIJ[3]+=SG*i3*j3;     \
    } while (0)

#define FOLDHALO(G, SG) do {                                                        \
        const unsigned ui_ = (hidx < 2) ? G.x : G.y;                                \
        const unsigned uj_ = (hidx < 2) ? G.z : G.w;                                \
        const float iv_ = (hidx & 1) ? uhi(ui_) : ulo(ui_);                         \
        const float jv_ = (hidx & 1) ? uhi(uj_) : ulo(uj_);                         \
        hs0 += SG*iv_; hs1 += SG*jv_;                                               \
        hs2 += SG*iv_*iv_; hs3 += SG*jv_*jv_; hs4 += SG*iv_*jv_;                    \
    } while (0)

// publish bf16-quantized vertical sums (own uint2 + halo u16)
#define PUB() do {                                                                  \
        uint2 p_;                                                                   \
        p_.x = pk2(sI[0],  sI[1]);  p_.y = pk2(sI[2],  sI[3]);                      \
        *(uint2*)&vs[0][4 + xw] = p_;                                               \
        p_.x = pk2(sJ[0],  sJ[1]);  p_.y = pk2(sJ[2],  sJ[3]);                      \
        *(uint2*)&vs[1][4 + xw] = p_;                                               \
        p_.x = pk2(sII[0], sII[1]); p_.y = pk2(sII[2], sII[3]);                     \
        *(uint2*)&vs[2][4 + xw] = p_;                                               \
        p_.x = pk2(sJJ[0], sJJ[1]); p_.y = pk2(sJJ[2], sJJ[3]);                     \
        *(uint2*)&vs[3][4 + xw] = p_;                                               \
        p_.x = pk2(sIJ[0], sIJ[1]); p_.y = pk2(sIJ[2], sIJ[3]);                     \
        *(uint2*)&vs[4][4 + xw] = p_;                                               \
        if (isH) {                                                                  \
            vs[0][hslot] = (unsigned short)pk2(hs0, 0.f);                           \
            vs[1][hslot] = (unsigned short)pk2(hs1, 0.f);                           \
            vs[2][hslot] = (unsigned short)pk2(hs2, 0.f);                           \
            vs[3][hslot] = (unsigned short)pk2(hs3, 0.f);                           \
            vs[4][hslot] = (unsigned short)pk2(hs4, 0.f);                           \
        }                                                                           \
    } while (0)

#define UNPK4(U, F) do {                                                            \
        F.x = ulo(U.x); F.y = uhi(U.x); F.z = ulo(U.y); F.w = uhi(U.y);             \
    } while (0)

#define HTAP(a, cg, T, o) do {                                                      \
        float s_ = a.x + a.y + a.z + a.w + cg.x + T;                                \
        o[0] = s_; s_ += cg.y - a.x;                                                \
        o[1] = s_; s_ += cg.z - a.y;                                                \
        o[2] = s_; s_ += cg.w - a.z;                                                \
        o[3] = s_;                                                                  \
    } while (0)

    // ---- init: rows y0-4 .. y0+4 -> ring slots 0..8, folded (+) ----
    FLOAD(y0 - 4);
    #pragma unroll 1
    for (int r = 0; r < 9; ++r) {
        uint4 pkv;
        PACKW(r);
        asm volatile("" ::: "memory");
        uint4 he = make_uint4(0, 0, 0, 0);
        if (isH) he = ring[r][hg8];
        asm volatile("" ::: "memory");
        FLOAD(y0 - 3 + r);             // r==8 loads y0+5: first enter row
        FOLDOWN(pkv, 1.0f);
        if (isH) FOLDHALO(he, 1.0f);
    }

    // ---- main: TY rows, slot s = k % 9; leave-read precedes same-slot enter-write ----
    int s = 0;
    #pragma unroll 1
    for (int k = 0; k < TY; ++k) {
        // 1) publish window(y0+k) (bf16); read neighbor halo sums
        PUB();
        asm volatile("" ::: "memory");
        uint2 ua0 = *(const uint2*)&vs[0][xw], uc0 = *(const uint2*)&vs[0][xw + 8];
        uint2 ua1 = *(const uint2*)&vs[1][xw], uc1 = *(const uint2*)&vs[1][xw + 8];
        uint2 ua2 = *(const uint2*)&vs[2][xw], uc2 = *(const uint2*)&vs[2][xw + 8];
        uint2 ua3 = *(const uint2*)&vs[3][xw], uc3 = *(const uint2*)&vs[3][xw + 8];
        uint2 ua4 = *(const uint2*)&vs[4][xw], uc4 = *(const uint2*)&vs[4][xw + 8];
        asm volatile("" ::: "memory");

        // 2) totals of window(y0+k) (exact f32 register sums)
        const float T0 = sI[0]  + sI[1]  + sI[2]  + sI[3];
        const float T1 = sJ[0]  + sJ[1]  + sJ[2]  + sJ[3];
        const float T2 = sII[0] + sII[1] + sII[2] + sII[3];
        const float T3 = sJJ[0] + sJJ[1] + sJJ[2] + sJJ[3];
        const float T4 = sIJ[0] + sIJ[1] + sIJ[2] + sIJ[3];

        // 3) leave reads from slot s, THEN overwrite slot s with the enter row
        uint4 lv = ring[s][lane + 1];
        uint4 lh = make_uint4(0, 0, 0, 0), he = make_uint4(0, 0, 0, 0);
        if (isH) lh = ring[s][hg8];
        asm volatile("" ::: "memory");
        uint4 pkv;
        PACKW(s);
        asm volatile("" ::: "memory");
        if (isH) he = ring[s][hg8];

        // 4) prefetch next enter row (global, read-once)
        FLOAD(y0 + 6 + k);

        // 5) horizontal 9-taps + cc for row y0+k (covers DS latency)
        float4 a0, a1, a2, a3, a4, c0, c1, c2, c3, c4;
        UNPK4(ua0, a0); UNPK4(uc0, c0);
        UNPK4(ua1, a1); UNPK4(uc1, c1);
        UNPK4(ua2, a2); UNPK4(uc2, c2);
        UNPK4(ua3, a3); UNPK4(uc3, c3);
        UNPK4(ua4, a4); UNPK4(uc4, c4);
        float h0[4], h1[4], h2[4], h3[4], h4[4];
        HTAP(a0, c0, T0, h0); HTAP(a1, c1, T1, h1); HTAP(a2, c2, T2, h2);
        HTAP(a3, c3, T3, h3); HTAP(a4, c4, T4, h4);
        #pragma unroll
        for (int c = 0; c < 4; ++c) {
            const float uI    = h0[c] * inv;
            const float uJ    = h1[c] * inv;
            const float cross = h4[c] * inv - uI * uJ;
            const float Iv    = h2[c] * inv - uI * uI;
            const float Jv    = h3[c] * inv - uJ * uJ;
            accv += cross * rsqrtf(fmaxf(Iv * Jv, 1e-7f));
        }

        // 6) slide: enter(+) / leave(-) — bit-identical packed values cancel exactly
        FOLDOWN(pkv, 1.0f);
        FOLDOWN(lv, -1.0f);
        if (isH) { FOLDHALO(he, 1.0f); FOLDHALO(lh, -1.0f); }

        s = (s == RS - 1) ? 0 : s + 1;
    }

#undef HTAP
#undef UNPK4
#undef PUB
#undef FOLDHALO
#undef FOLDOWN
#undef PACKW
#undef FLOAD

    // wave reduce -> bucketed atomics
    #pragma unroll
    for (int off = 32; off > 0; off >>= 1)
        accv += __shfl_down(accv, off);
    if (lane == 0)
        atomicAdd(&acc[n & (NBK - 1)], (double)accv);
}

extern "C" void kernel_launch(void* const* d_in, const int* in_sizes, int n_in,
                              void* d_out, int out_size, void* d_ws, size_t ws_size,
                              hipStream_t stream) {
    const float* y_pred = (const float*)d_in[0];  // Ji
    const float* y_true = (const float*)d_in[1];  // Ii
    float* out = (float*)d_out;
    double* accp = (double*)d_ws;

    ncc_zero<<<dim3(1), dim3(NBK), 0, stream>>>(accp);
    // 8 img x 4 panels x 128 strips = 4096 one-wave blocks; LDS ~12.1 KB ->
    // ~13 resident blocks/CU (was 8); RS=9 ring + bf16 vs shrink the footprint
    ncc_main<<<dim3(8 * 4 * (H / TY)), dim3(NT), 0, stream>>>(y_pred, y_true, accp);
    ncc_finalize<<<dim3(1), dim3(1), 0, stream>>>(accp, out);
}

// Round 23
// 37.289 us; speedup vs baseline: 5.0262x; 1.2623x over previous
//
#include <hip/hip_runtime.h>

#define H 1024
#define W 1024
#define TY 16
#define NT 64               /* one wave per block */
#define RS 10               /* ring slots (distance 9 + 1) */
#define NG 66               /* uint4 groups/slot: 1 halo + 64 own + 1 halo */
#define LW 264              /* vs cols: 4 pad + 256 + 4 pad */
#define NBK 64              /* reduction buckets */

__global__ void ncc_zero(double* acc) {
    if (threadIdx.x < NBK) acc[threadIdx.x] = 0.0;
}

__global__ void ncc_finalize(const double* __restrict__ acc, float* __restrict__ out) {
    double s = 0.0;
    #pragma unroll
    for (int i = 0; i < NBK; ++i) s += acc[i];
    out[0] = 1.0f - (float)(s * (1.0 / 8388608.0));
}

__device__ __forceinline__ unsigned pk2(float lo, float hi) {
    unsigned r;
    asm("v_cvt_pk_bf16_f32 %0, %1, %2" : "=v"(r) : "v"(lo), "v"(hi));
    return r;
}
__device__ __forceinline__ float ulo(unsigned u) { return __uint_as_float(u << 16); }
__device__ __forceinline__ float uhi(unsigned u) { return __uint_as_float(u & 0xffff0000u); }

__global__ __launch_bounds__(NT) void ncc_main(
    const float* __restrict__ Jg,  // y_pred
    const float* __restrict__ Ig,  // y_true
    double* __restrict__ acc)
{
    __shared__ uint4 ring[RS][NG];     // bf16 rows {i01,i23,j01,j23}/group: 10.3 KB
    __shared__ float vs[5][LW];        // vertical sums I,J,II,JJ,IJ: 5.3 KB

    const int n     = blockIdx.x;
    const int b     = n & 7;           // image (== XCD round-robin)
    const int rest  = n >> 3;
    const int panel = rest & 3;
    const int strip = rest >> 2;
    const int y0    = strip * TY;
    const int lane  = threadIdx.x;
    const int wb    = panel << 8;
    const int x0    = wb + (lane << 2);
    const int xw    = lane << 2;       // vs read base; own at xw+4

    const float* __restrict__ Ib = Ig + (size_t)b * (H * W);
    const float* __restrict__ Jb = Jg + (size_t)b * (H * W);

    // ring halo writers: lane 0 -> group 0 (cols wb-4..wb-1), lane 1 -> group 65
    const bool  hw  = (lane < 2);
    const int   hx  = (lane == 0) ? (wb - 4) : (wb + 256);
    const float mhx = (hw && (unsigned)hx <= (unsigned)(W - 4)) ? 1.0f : 0.0f;
    const int   hxc = min(max(hx, 0), W - 4);
    const int   hgw = (lane == 0) ? 0 : (NG - 1);

    // halo-sum owners: lanes 0..7, one col each (0-3 left, 4-7 right), both images
    const bool  isH   = (lane < 8);
    const int   hg8   = (lane < 4) ? 0 : (NG - 1);
    const int   hidx  = lane & 3;
    const int   hslot = (lane < 4) ? lane : (256 + lane);   // vs pad cols 0-3 / 260-263

    float sI[4]={0,0,0,0}, sJ[4]={0,0,0,0}, sII[4]={0,0,0,0}, sJJ[4]={0,0,0,0}, sIJ[4]={0,0,0,0};
    float hs0=0, hs1=0, hs2=0, hs3=0, hs4=0;
    float accv = 0.0f;
    const float inv = 1.0f / 81.0f;

    float4 Pi, Pj, Phi = {0,0,0,0}, Phj = {0,0,0,0};
    float  Pm;

#define FLOAD(yy) do {                                                              \
        const int r_ = (yy);                                                        \
        Pm = ((unsigned)r_ < (unsigned)H) ? 1.0f : 0.0f;                            \
        const int rc_ = min(max(r_, 0), H - 1);                                     \
        Pi = *(const float4*)(Ib + (size_t)rc_ * W + x0);                           \
        Pj = *(const float4*)(Jb + (size_t)rc_ * W + x0);                           \
        if (hw) {                                                                   \
            Phi = *(const float4*)(Ib + (size_t)rc_ * W + hxc);                     \
            Phj = *(const float4*)(Jb + (size_t)rc_ * W + hxc);                     \
        }                                                                           \
    } while (0)

// pack current P-regs, write ring slot; leaves packed own-row in `pkv`
#define PACKW(sl) do {                                                              \
        pkv.x = pk2(Pi.x * Pm, Pi.y * Pm);                                          \
        pkv.y = pk2(Pi.z * Pm, Pi.w * Pm);                                          \
        pkv.z = pk2(Pj.x * Pm, Pj.y * Pm);                                          \
        pkv.w = pk2(Pj.z * Pm, Pj.w * Pm);                                          \
        ring[sl][lane + 1] = pkv;                                                   \
        if (hw) {                                                                   \
            const float mm_ = Pm * mhx;                                             \
            uint4 h_;                                                               \
            h_.x = pk2(Phi.x * mm_, Phi.y * mm_);                                   \
            h_.y = pk2(Phi.z * mm_, Phi.w * mm_);                                   \
            h_.z = pk2(Phj.x * mm_, Phj.y * mm_);                                   \
            h_.w = pk2(Phj.z * mm_, Phj.w * mm_);                                   \
            ring[sl][hgw] = h_;                                                     \
        }                                                                           \
    } while (0)

// fold packed own-4-col group into register vertical sums, sign SG
#define FOLDOWN(G, SG) do {                                                         \
        const float i0=ulo(G.x), i1=uhi(G.x), i2=ulo(G.y), i3=uhi(G.y);             \
        const float j0=ulo(G.z), j1=uhi(G.z), j2=ulo(G.w), j3=uhi(G.w);             \
        sI[0]+=SG*i0; sI[1]+=SG*i1; sI[2]+=SG*i2; sI[3]+=SG*i3;                     \
        sJ[0]+=SG*j0; sJ[1]+=SG*j1; sJ[2]+=SG*j2; sJ[3]+=SG*j3;                     \
        sII[0]+=SG*i0*i0; sII[1]+=SG*i1*i1; sII[2]+=SG*i2*i2; sII[3]+=SG*i3*i3;     \
        sJJ[0]+=SG*j0*j0; sJJ[1]+=SG*j1*j1; sJJ[2]+=SG*j2*j2; sJJ[3]+=SG*j3*j3;     \
        sIJ[0]+=SG*i0*j0; sIJ[1]+=SG*i1*j1; sIJ[2]+=SG*i2*j2; sIJ[3]+=SG*i3*j3;     \
    } while (0)

// fold one halo col (lanes 0..7) from packed halo group, sign SG
#define FOLDHALO(G, SG) do {                                                        \
        const unsigned ui_ = (hidx < 2) ? G.x : G.y;                                \
        const unsigned uj_ = (hidx < 2) ? G.z : G.w;                                \
        const float iv_ = (hidx & 1) ? uhi(ui_) : ulo(ui_);                         \
        const float jv_ = (hidx & 1) ? uhi(uj_) : ulo(uj_);                         \
        hs0 += SG*iv_; hs1 += SG*jv_;                                               \
        hs2 += SG*iv_*iv_; hs3 += SG*jv_*jv_; hs4 += SG*iv_*jv_;                    \
    } while (0)

#define PUB() do {                                                                  \
        *(float4*)&vs[0][4 + xw] = make_float4(sI[0],  sI[1],  sI[2],  sI[3]);      \
        *(float4*)&vs[1][4 + xw] = make_float4(sJ[0],  sJ[1],  sJ[2],  sJ[3]);      \
        *(float4*)&vs[2][4 + xw] = make_float4(sII[0], sII[1], sII[2], sII[3]);     \
        *(float4*)&vs[3][4 + xw] = make_float4(sJJ[0], sJJ[1], sJJ[2], sJJ[3]);     \
        *(float4*)&vs[4][4 + xw] = make_float4(sIJ[0], sIJ[1], sIJ[2], sIJ[3]);     \
        if (isH) {                                                                  \
            vs[0][hslot] = hs0; vs[1][hslot] = hs1; vs[2][hslot] = hs2;             \
            vs[3][hslot] = hs3; vs[4][hslot] = hs4;                                 \
        }                                                                           \
    } while (0)

#define HTAP(a, cg, T, o) do {                                                      \
        float s_ = a.x + a.y + a.z + a.w + cg.x + T;                                \
        o[0] = s_; s_ += cg.y - a.x;                                                \
        o[1] = s_; s_ += cg.z - a.y;                                                \
        o[2] = s_; s_ += cg.w - a.z;                                                \
        o[3] = s_;                                                                  \
    } while (0)

    // ---- init: rows y0-4 .. y0+4 -> ring slots 0..8, folded (+) ----
    FLOAD(y0 - 4);
    #pragma unroll 1
    for (int r = 0; r < 9; ++r) {
        uint4 pkv;
        PACKW(r);
        asm volatile("" ::: "memory");
        uint4 he = make_uint4(0, 0, 0, 0);
        if (isH) he = ring[r][hg8];
        asm volatile("" ::: "memory");
        FLOAD(y0 - 3 + r);             // r==8 loads y0+5: first enter row
        FOLDOWN(pkv, 1.0f);
        if (isH) FOLDHALO(he, 1.0f);
    }

    // ---- main: TY rows; uniform iteration (last slide is harmless extra) ----
    int ls = 0, es = 9;
    #pragma unroll 1
    for (int k = 0; k < TY; ++k) {
        // 1) publish window(y0+k); read neighbor halos
        PUB();
        asm volatile("" ::: "memory");
        float4 a0 = *(const float4*)&vs[0][xw], c0 = *(const float4*)&vs[0][xw + 8];
        float4 a1 = *(const float4*)&vs[1][xw], c1 = *(const float4*)&vs[1][xw + 8];
        float4 a2 = *(const float4*)&vs[2][xw], c2 = *(const float4*)&vs[2][xw + 8];
        float4 a3 = *(const float4*)&vs[3][xw], c3 = *(const float4*)&vs[3][xw + 8];
        float4 a4 = *(const float4*)&vs[4][xw], c4 = *(const float4*)&vs[4][xw + 8];
        asm volatile("" ::: "memory");

        // 2) totals of window(y0+k) before sliding
        const float T0 = sI[0]  + sI[1]  + sI[2]  + sI[3];
        const float T1 = sJ[0]  + sJ[1]  + sJ[2]  + sJ[3];
        const float T2 = sII[0] + sII[1] + sII[2] + sII[3];
        const float T3 = sJJ[0] + sJJ[1] + sJJ[2] + sJJ[3];
        const float T4 = sIJ[0] + sIJ[1] + sIJ[2] + sIJ[3];

        // 3) enter row -> ring; issue leave reads (ring) + halo reads
        uint4 pkv;
        PACKW(es);
        asm volatile("" ::: "memory");
        uint4 lv = ring[ls][lane + 1];
        uint4 he = make_uint4(0, 0, 0, 0), hl = make_uint4(0, 0, 0, 0);
        if (isH) { he = ring[es][hg8]; hl = ring[ls][hg8]; }
        asm volatile("" ::: "memory");

        // 4) prefetch next enter row (global, read-once)
        FLOAD(y0 + 6 + k);

        // 5) cc for row y0+k (covers DS latency of lv/he/hl)
        float h0[4], h1[4], h2[4], h3[4], h4[4];
        HTAP(a0, c0, T0, h0); HTAP(a1, c1, T1, h1); HTAP(a2, c2, T2, h2);
        HTAP(a3, c3, T3, h3); HTAP(a4, c4, T4, h4);
        #pragma unroll
        for (int c = 0; c < 4; ++c) {
            const float uI    = h0[c] * inv;
            const float uJ    = h1[c] * inv;
            const float cross = h4[c] * inv - uI * uJ;
            const float Iv    = h2[c] * inv - uI * uI;
            const float Jv    = h3[c] * inv - uJ * uJ;
            accv += cross * rsqrtf(fmaxf(Iv * Jv, 1e-7f));
        }

        // 6) slide: fold enter(+) / leave(-) — bit-identical packed values cancel
        FOLDOWN(pkv, 1.0f);
        FOLDOWN(lv, -1.0f);
        if (isH) { FOLDHALO(he, 1.0f); FOLDHALO(hl, -1.0f); }

        ls = (ls == RS - 1) ? 0 : ls + 1;
        es = (es == RS - 1) ? 0 : es + 1;
    }

#undef HTAP
#undef PUB
#undef FOLDHALO
#undef FOLDOWN
#undef PACKW
#undef FLOAD

    // wave reduce -> bucketed atomics
    #pragma unroll
    for (int off = 32; off > 0; off >>= 1)
        accv += __shfl_down(accv, off);
    if (lane == 0)
        atomicAdd(&acc[n & (NBK - 1)], (double)accv);
}

extern "C" void kernel_launch(void* const* d_in, const int* in_sizes, int n_in,
                              void* d_out, int out_size, void* d_ws, size_t ws_size,
                              hipStream_t stream) {
    const float* y_pred = (const float*)d_in[0];  // Ji
    const float* y_true = (const float*)d_in[1];  // Ii
    float* out = (float*)d_out;
    double* accp = (double*)d_ws;

    ncc_zero<<<dim3(1), dim3(NBK), 0, stream>>>(accp);
    // 8 img x 4 panels x 64 strips = 2048 one-wave blocks; 15.8 KB LDS;
    // register vertical sums (cheap slide) + bf16 ring (no global leave loads)
    ncc_main<<<dim3(8 * 4 * (H / TY)), dim3(NT), 0, stream>>>(y_pred, y_true, accp);
    ncc_finalize<<<dim3(1), dim3(1), 0, stream>>>(accp, out);
}